// Round 22
// baseline (228.315 us; speedup 1.0000x reference)
//
#include <hip/hip_runtime.h>
#include <hip/hip_bf16.h>
#include <type_traits>

#define B_ 2
#define T_ 2048
#define DM_ 2048
#define H_ 16
#define KV_ 4
#define HD_ 128
#define M_ 4096   // B_*T_
#define QKVN 3072 // H*HD + 2*KV*HD

typedef __attribute__((ext_vector_type(8))) short bf16x8;
typedef __attribute__((ext_vector_type(4))) float f32x4;
typedef __attribute__((ext_vector_type(4))) short s16x4;
typedef unsigned short u16;
typedef unsigned int u32;
typedef __attribute__((address_space(1))) unsigned int as1_u32;
typedef __attribute__((address_space(3))) unsigned int as3_u32;

__device__ inline u16 f2b(float f){
  __hip_bfloat16 h = __float2bfloat16(f);
  return *reinterpret_cast<u16*>(&h);
}
__device__ inline float b2f(u16 u){
  __hip_bfloat16 h = *reinterpret_cast<__hip_bfloat16*>(&u);
  return __bfloat162float(h);
}
__device__ inline f32x4 mfma16(bf16x8 a, bf16x8 b, f32x4 c){
  return __builtin_amdgcn_mfma_f32_16x16x32_bf16(a, b, c, 0, 0, 0);
}

// ---------------- fused prep: cvt + rope_table + 4x weight transpose ----------------
__global__ __launch_bounds__(256) void prep_kernel(const float* __restrict__ x,
                                                   const float* __restrict__ Wq,
                                                   const float* __restrict__ Wk,
                                                   const float* __restrict__ Wv,
                                                   const float* __restrict__ Wo,
                                                   u16* __restrict__ xb,
                                                   u16* __restrict__ wT,
                                                   u16* __restrict__ woT,
                                                   float2* __restrict__ tab)
{
  const int bid = blockIdx.x;
  const int tid = threadIdx.x;
  if (bid < 8192){
    int i = (bid*256 + tid)*4;
    float4 v = *reinterpret_cast<const float4*>(x + i);
    s16x4 o;
    o[0] = (short)f2b(v.x); o[1] = (short)f2b(v.y);
    o[2] = (short)f2b(v.z); o[3] = (short)f2b(v.w);
    *reinterpret_cast<s16x4*>(xb + i) = o;
    return;
  }
  if (bid < 8704){
    int idx = (bid-8192)*256 + tid;   // t*64 + d
    int t = idx >> 6, d = idx & 63;
    float inv = exp2f((float)d * -0.2076205059304601f);
    float sn, cs;
    sincosf((float)t * inv, &sn, &cs);
    tab[idx] = float2{cs, sn};
    return;
  }
  int r = bid - 8704;
  const float* W; u16* Wt; int N, nx;
  if (r < 4096)      { W = Wq; Wt = wT;               N = 2048; nx = 64; }
  else if (r < 5120) { W = Wk; Wt = wT + 2048*2048;   N = 512;  nx = 16; r -= 4096; }
  else if (r < 6144) { W = Wv; Wt = wT + 2560*2048;   N = 512;  nx = 16; r -= 5120; }
  else               { W = Wo; Wt = woT;              N = 2048; nx = 64; r -= 6144; }
  const int n0 = (r % nx)*32, k0 = (r / nx)*32;
  const int tx = tid & 31, ty = tid >> 5;
  __shared__ float tile[32][33];
#pragma unroll
  for (int i=0;i<4;i++)
    tile[ty+8*i][tx] = W[(size_t)(k0+ty+8*i)*N + n0 + tx];
  __syncthreads();
#pragma unroll
  for (int i=0;i<4;i++)
    Wt[(size_t)(n0+ty+8*i)*2048 + k0 + tx] = f2b(tile[tx][ty+8*i]);
}

// ---------------- fused mid: RoPE apply (Q+K) + transpose_v ----------------
__global__ __launch_bounds__(256) void mid_kernel(u16* __restrict__ qkv, const float2* __restrict__ tab,
                                                  u16* __restrict__ vt)
{
  const int bid = blockIdx.x;
  const int tid = threadIdx.x;
  if (bid < 10240){
    u16* qk; int lognh, idx;
    if (bid < 8192){ qk = qkv;        lognh = 4; idx = bid*256 + tid; }
    else           { qk = qkv + 2048; lognh = 2; idx = (bid-8192)*256 + tid; }
    int dp = idx & 31;
    int rh = idx >> 5;
    int nh = 1 << lognh;
    int h = rh & (nh-1);
    int row = rh >> lognh;
    if (row >= M_) return;
    int t = row & (T_-1);
    float4 cn = *reinterpret_cast<const float4*>(tab + t*64 + 2*dp);
    size_t base = (size_t)row*QKVN + h*HD_ + 2*dp;
    u32 lo = *reinterpret_cast<const u32*>(qk + base);
    u32 hi = *reinterpret_cast<const u32*>(qk + base + 64);
    float a0 = b2f(lo & 0xffff), a1 = b2f(lo >> 16);
    float b0 = b2f(hi & 0xffff), b1 = b2f(hi >> 16);
    u32 nlo = (u32)f2b(a0*cn.x - b0*cn.y) | ((u32)f2b(a1*cn.z - b1*cn.w) << 16);
    u32 nhi = (u32)f2b(b0*cn.x + a0*cn.y) | ((u32)f2b(b1*cn.z + a1*cn.w) << 16);
    *reinterpret_cast<u32*>(qk + base)      = nlo;
    *reinterpret_cast<u32*>(qk + base + 64) = nhi;
    return;
  }
  const int bid2 = bid - 10240;
  const int t0 = (bid2 & 63)*32;
  const int d0 = ((bid2>>6)&3)*32;
  const int bk = bid2>>8;
  const int bb = bk >> 2, kv = bk & 3;
  const int tx = tid & 31, ty = tid >> 5;
  __shared__ u16 tile[32][33];
#pragma unroll
  for (int i=0;i<4;i++)
    tile[ty+8*i][tx] = qkv[(size_t)(bb*T_ + t0+ty+8*i)*QKVN + 2560 + kv*HD_ + d0 + tx];
  __syncthreads();
#pragma unroll
  for (int i=0;i<4;i++)
    vt[(size_t)(bk*HD_ + d0+ty+8*i)*T_ + t0 + tx] = tile[tx][ty+8*i];
}

// ---------------- bf16 GEMM v3: 256-row tile, double-buffered LDS, counted vmcnt ----------------
__device__ inline void cstore(float* p, float v){ *p = v; }
__device__ inline void cstore(u16* p, float v){ *p = f2b(v); }

template<typename CT, int BN, int NWC>
__global__ __launch_bounds__(512, 2) void gemm_db(const u16* __restrict__ A, const u16* __restrict__ BT,
                                                  CT* __restrict__ C, int M, int N, int K)
{
  constexpr int AP = 4;
  constexpr int BP = BN/64;
  constexpr int MR = 2*NWC;
  __shared__ u16 Als[2][256*64];
  __shared__ u16 Bls[2][BN*64];

  const int tid = threadIdx.x;
  const int wave = tid>>6, lane = tid&63;
  const int gl = lane>>4, qcl = lane&15;
  const int gx = gridDim.x;
  int wid = blockIdx.y*gx + blockIdx.x;
  const int cpx = (gx*gridDim.y) >> 3;
  wid = (wid & 7)*cpx + (wid >> 3);
  const int m0 = (wid / gx)*256, n0 = (wid % gx)*BN;
  const int wr = (wave / NWC)*(16*MR);
  const int wc = (wave % NWC)*64;

  f32x4 acc[MR][4];
#pragma unroll
  for (int i=0;i<MR;i++)
#pragma unroll
    for (int j=0;j<4;j++) acc[i][j] = f32x4{0.f,0.f,0.f,0.f};

  const u16* srcA[AP];
  const u16* srcB[BP];
#pragma unroll
  for (int p=0;p<AP;p++){
    const int D = p*8192 + tid*16;
    const int row = D>>7;
    const int colb = (((D>>4)&7) ^ (row&7))*8;
    srcA[p] = A + (size_t)(m0+row)*K + colb;
  }
#pragma unroll
  for (int p=0;p<BP;p++){
    const int D = p*8192 + tid*16;
    const int row = D>>7;
    const int colb = (((D>>4)&7) ^ (row&7))*8;
    srcB[p] = BT + (size_t)(n0+row)*K + colb;
  }

  auto stage = [&](int buf){
#pragma unroll
    for (int p=0;p<AP;p++)
      __builtin_amdgcn_global_load_lds((as1_u32*)srcA[p],
        (as3_u32*)((char*)&Als[buf][0] + p*8192 + wave*1024), 16, 0, 0);
#pragma unroll
    for (int p=0;p<BP;p++)
      __builtin_amdgcn_global_load_lds((as1_u32*)srcB[p],
        (as3_u32*)((char*)&Bls[buf][0] + p*8192 + wave*1024), 16, 0, 0);
#pragma unroll
    for (int p=0;p<AP;p++) srcA[p] += 64;
#pragma unroll
    for (int p=0;p<BP;p++) srcB[p] += 64;
  };

  auto compute = [&](int buf){
#pragma unroll
    for (int kk=0;kk<2;kk++){
      bf16x8 af[MR], bfr[4];
#pragma unroll
      for (int mi=0;mi<MR;mi++){
        const int row = wr + mi*16 + qcl;
        af[mi] = *reinterpret_cast<const bf16x8*>((char*)&Als[buf][0] + row*128 + (((kk<<2)+gl) ^ (qcl&7))*16);
      }
#pragma unroll
      for (int ni=0;ni<4;ni++){
        const int row = wc + ni*16 + qcl;
        bfr[ni] = *reinterpret_cast<const bf16x8*>((char*)&Bls[buf][0] + row*128 + (((kk<<2)+gl) ^ (qcl&7))*16);
      }
      __builtin_amdgcn_s_setprio(1);
#pragma unroll
      for (int mi=0;mi<MR;mi++)
#pragma unroll
        for (int ni=0;ni<4;ni++)
          acc[mi][ni] = mfma16(af[mi], bfr[ni], acc[mi][ni]);
      __builtin_amdgcn_s_setprio(0);
    }
  };

  const int NT = K >> 6;
  stage(0);
  for (int t=0; t<NT; t++){
    const int cur = t&1;
    if (t+1 < NT){
      stage(cur^1);
      if constexpr (AP+BP == 8) asm volatile("s_waitcnt vmcnt(8)" ::: "memory");
      else                      asm volatile("s_waitcnt vmcnt(6)" ::: "memory");
    } else {
      asm volatile("s_waitcnt vmcnt(0)" ::: "memory");
    }
    __builtin_amdgcn_s_barrier();
    compute(cur);
    __builtin_amdgcn_s_barrier();
  }

#pragma unroll
  for (int mi=0;mi<MR;mi++)
#pragma unroll
    for (int ni=0;ni<4;ni++)
#pragma unroll
      for (int j=0;j<4;j++){
        int row = m0 + wr + mi*16 + (lane>>4)*4 + j;
        int col = n0 + wc + ni*16 + (lane&15);
        cstore(C + (size_t)row*N + col, acc[mi][ni][j]);
      }
}

// ---------------- causal GQA flash attention (v16: fully per-qs QK+softmax, min live range) ----------------
__device__ inline const u16* slot_cptr(const u16* pout, const u16* pwt, int u){
  return (u < 4096) ? (pout + (size_t)u*4096) : (pwt + (size_t)(u-4096)*4096);
}

__global__ __launch_bounds__(256, 3) void attn_kernel(const u16* __restrict__ qkv,
                                                      const u16* __restrict__ Vt,
                                                      u16* __restrict__ pout,
                                                      u16* __restrict__ pwt,
                                                      float* __restrict__ ml,
                                                      u16* __restrict__ ao)
{
  __shared__ u16 Ktile[2][4096];    // 2 x 8 KB, swizzled
  __shared__ u16 Vtile[2][4096];    // 2 x 8 KB, swizzled
  __shared__ u16 plds[4][32*40];    // per-wave P roundtrip
  const int wave = threadIdx.x>>6, lane = threadIdx.x&63;
  const int g = lane>>4, qc = lane&15;

  const int bh = blockIdx.x & 31;
  const int rem = blockIdx.x >> 5;  // 0..39
  int q4, e;
  if (rem < 4)       { q4=0; e=rem; }
  else if (rem < 12) { q4=1; e=rem-4; }
  else if (rem < 24) { q4=2; e=rem-12; }
  else               { q4=3; e=rem-24; }
  const int j  = q4*4 + e/(q4+1);
  const int c  = e%(q4+1);
  const int nc = q4 + 1;            // chunks for this q-group
  const int qt = j*4 + wave;        // this wave's 32-row q-tile
  const int ntg = j*4 + 4;          // staged tiles go to the group's max diagonal
  const int tstart = 16*c;
  const int tcnt = min(16, ntg - tstart);

  const int h = bh & (H_-1), b = bh >> 4;
  const int kv = h >> 2;

  const u16* qbase = qkv + (size_t)(b*T_ + qt*32)*QKVN + h*HD_ + 8*g;
  bf16x8 qf[2][4];
#pragma unroll
  for (int qs=0; qs<2; qs++)
#pragma unroll
    for (int d4=0; d4<4; d4++)
      qf[qs][d4] = *reinterpret_cast<const bf16x8*>(qbase + (size_t)(qs*16+qc)*QKVN + d4*32);

  const char* Kbase = (const char*)(qkv + (size_t)(b*T_)*QKVN + 2048 + kv*HD_);
  const char* Vbase = (const char*)(Vt + (size_t)(b*KV_+kv)*HD_*T_);
  const char* Ktc = (const char*)&Ktile[0][0];
  const char* Vtc = (const char*)&Vtile[0][0];

  f32x4 oacc[2][8];
#pragma unroll
  for (int qs=0; qs<2; qs++)
#pragma unroll
    for (int dt=0; dt<8; dt++) oacc[qs][dt] = f32x4{0.f,0.f,0.f,0.f};
  float mrun[2] = {-1e30f, -1e30f};
  float lrun[2] = {0.f, 0.f};
  const float SCALE = 0.08838834764831845f;
  const float L2E = 1.4426950408889634f;
  const float DEFER = 8.f;          // T13
  u16* pw = &plds[wave][0];

  auto compute = [&](int t, int half, auto mc){
    constexpr bool masked = decltype(mc)::value;
    const int s0 = t*32;
    const int hb = half*8192;       // byte offset of buffer half
    // fully per-qs: QK MFMA (K frags re-read from LDS per qs), softmax, P-pack.
    // Minimizes simultaneously-live sacc+p registers (spill control).
#pragma unroll
    for (int qs=0; qs<2; qs++){
      f32x4 sacc[2];
#pragma unroll
      for (int ss=0; ss<2; ss++) sacc[ss] = f32x4{0.f,0.f,0.f,0.f};
      __builtin_amdgcn_s_setprio(1);
#pragma unroll
      for (int d4=0; d4<4; d4++)
#pragma unroll
        for (int ss=0; ss<2; ss++){
          int A = ((ss*16+qc)<<8) + (d4<<6) + (g<<4);
          A ^= (qc&7)<<4;                    // K un-swizzle (row&7 == qc&7)
          bf16x8 kf = *reinterpret_cast<const bf16x8*>(Ktc + hb + A);
          sacc[ss] = mfma16(kf, qf[qs][d4], sacc[ss]);
        }
      __builtin_amdgcn_s_setprio(0);

      float p[8];
      float tm = -1e30f;
#pragma unroll
      for (int ss=0; ss<2; ss++)
#pragma unroll
        for (int jj=0; jj<4; jj++){
          float v = sacc[ss][jj]*SCALE;
          if constexpr (masked){
            int sg = s0 + ss*16 + g*4 + jj;
            if (sg > qt*32 + qs*16 + qc) v = -1e30f;
          }
          p[ss*4+jj] = v;
          tm = fmaxf(tm, v);
        }
      tm = fmaxf(tm, __shfl_xor(tm, 16));
      tm = fmaxf(tm, __shfl_xor(tm, 32));
      float mnew = fmaxf(mrun[qs], tm);
      if (tm - mrun[qs] <= DEFER) mnew = mrun[qs];   // defer-max
      float al = exp2f((mrun[qs]-mnew)*L2E);
      float rs = 0.f;
#pragma unroll
      for (int i=0;i<8;i++){ p[i] = exp2f((p[i]-mnew)*L2E); rs += p[i]; }
      rs += __shfl_xor(rs, 16);
      rs += __shfl_xor(rs, 32);
      lrun[qs] = lrun[qs]*al + rs;
      mrun[qs] = mnew;
      if (!__all(al==1.f)){
        float aj[4];
#pragma unroll
        for (int jj=0; jj<4; jj++) aj[jj] = __shfl(al, g*4+jj);
#pragma unroll
        for (int dt=0; dt<8; dt++)
#pragma unroll
          for (int jj=0; jj<4; jj++) oacc[qs][dt][jj] *= aj[jj];
      }
#pragma unroll
      for (int ss=0; ss<2; ss++){
        unsigned w0 = (unsigned)f2b(p[ss*4+0]) | ((unsigned)f2b(p[ss*4+1])<<16);
        unsigned w1 = (unsigned)f2b(p[ss*4+2]) | ((unsigned)f2b(p[ss*4+3])<<16);
        *reinterpret_cast<unsigned*>(pw + (qs*16+qc)*40 + ss*16 + g*4)     = w0;
        *reinterpret_cast<unsigned*>(pw + (qs*16+qc)*40 + ss*16 + g*4 + 2) = w1;
      }
    }
    bf16x8 pf[2];
#pragma unroll
    for (int qs=0; qs<2; qs++)
      pf[qs] = *reinterpret_cast<const bf16x8*>(pw + (qs*16+qc)*40 + 8*g);
    __builtin_amdgcn_s_setprio(1);
#pragma unroll
    for (int dt=0; dt<8; dt++){
      int A = ((dt*16+qc)<<6) + (g<<4);
      A ^= ((qc>>1)&3)<<4;                   // V un-swizzle ((row>>1)&3 == (qc>>1)&3)
      bf16x8 vf = *reinterpret_cast<const bf16x8*>(Vtc + hb + A);
#pragma unroll
      for (int qs=0; qs<2; qs++)
        oacc[qs][dt] = mfma16(pf[qs], vf, oacc[qs][dt]);
    }
    __builtin_amdgcn_s_setprio(0);
  };
  using Tc = std::integral_constant<bool,true>;
  using Fc = std::integral_constant<bool,false>;

  // ---- main loop: stage 2 tiles (shared) -> barrier -> compute 2 ----
  const int npair = (tcnt+1)>>1;
  for (int ip = 0; ip < npair; ip++){
    const int t0 = tstart + 2*ip;
    const int ntile = min(2, tstart + tcnt - t0);
    __syncthreads();                          // previous tiles' LDS reads done
#pragma unroll
    for (int tt=0; tt<2; tt++){
      if (tt < ntile){
        const size_t r0 = (size_t)(t0+tt)*32;
#pragma unroll
        for (int c2=0; c2<2; c2++){
          const int cc = wave*2 + c2;
          const int D = cc*1024 + lane*16;
          // K: [32 s][128 d] rows 256B, swizzle byte ^= (row&7)<<4
          {
            const int LK = D ^ (((D>>8)&7)<<4);
            const char* src = Kbase + (r0 + (size_t)(D>>8))*(QKVN*2) + (LK & 255);
            __builtin_amdgcn_global_load_lds((as1_u32*)src,
              (as3_u32*)((char*)&Ktile[0][0] + tt*8192 + cc*1024), 16, 0, 0);
          }
          // V^T: [128 d][32 s] rows 64B, swizzle byte ^= ((row>>1)&3)<<4
          {
            const int LV = (D&63) ^ (((D>>7)&3)<<4);
            const char* src = Vbase + ((size_t)(D>>6)*T_ + r0 + (LV>>1))*2;
            __builtin_amdgcn_global_load_lds((as1_u32*)src,
              (as3_u32*)((char*)&Vtile[0][0] + tt*8192 + cc*1024), 16, 0, 0);
          }
        }
      }
    }
    __syncthreads();                          // vmcnt drained before barrier -> tiles ready
    if (t0 < qt)       compute(t0,   0, Fc{});
    else if (t0 == qt) compute(t0,   0, Tc{});
    if (ntile > 1){
      if (t0+1 < qt)       compute(t0+1, 1, Fc{});
      else if (t0+1 == qt) compute(t0+1, 1, Tc{});
    }
  }

  if (nc == 1){
    // qt < 16: finalize directly
    float lj0[4], lj1[4];
    float li0 = 1.f/lrun[0], li1 = 1.f/lrun[1];
#pragma unroll
    for (int jj=0; jj<4; jj++){
      lj0[jj] = __shfl(li0, g*4+jj);
      lj1[jj] = __shfl(li1, g*4+jj);
    }
    u16* ob = ao + (size_t)(b*T_ + qt*32)*(H_*HD_) + h*HD_;
#pragma unroll
    for (int dt=0; dt<8; dt++)
#pragma unroll
      for (int jj=0; jj<4; jj++){
        ob[(size_t)(g*4+jj)*(H_*HD_) + dt*16 + qc]      = f2b(oacc[0][dt][jj]*lj0[jj]);
        ob[(size_t)(16 + g*4+jj)*(H_*HD_) + dt*16 + qc] = f2b(oacc[1][dt][jj]*lj1[jj]);
      }
  } else {
    // slot = bh*144 + off(qt) + c
    int off;
    if (qt < 32)      off = (qt-16)*2;
    else if (qt < 48) off = 32 + (qt-32)*3;
    else              off = 80 + (qt-48)*4;
    const int u = bh*144 + off + c;
    u16* ob = (u < 4096) ? (pout + (size_t)u*4096) : (pwt + (size_t)(u-4096)*4096);
#pragma unroll
    for (int qs=0; qs<2; qs++)
#pragma unroll
      for (int dt=0; dt<8; dt++)
#pragma unroll
        for (int jj=0; jj<4; jj++)
          ob[(size_t)(qs*16 + g*4+jj)*128 + dt*16 + qc] = f2b(oacc[qs][dt][jj]);
    if (lane < 16){
      float* mlb = ml + (size_t)u*64;
#pragma unroll
      for (int qs=0; qs<2; qs++){
        mlb[qs*16 + lane]      = mrun[qs];
        mlb[32 + qs*16 + lane] = lrun[qs];
      }
    }
  }
}

// ---------------- combine partials (qt>=16) -> attention output (bf16) ----------------
__global__ void combine_kernel(const u16* __restrict__ pout, const u16* __restrict__ pwt,
                               const float* __restrict__ ml, u16* __restrict__ ao)
{
  const float L2E = 1.4426950408889634f;
  int idx = blockIdx.x*256 + threadIdx.x;   // 786432 threads
  int dg = idx & 15;
  int r  = (idx >> 4) & 31;
  int t  = idx >> 9;            // [0, 1536)
  int bh = t/48, qi = t%48;
  int qt = 16 + qi;
  int nc, off;
  if (qt < 32)      { nc = 2; off = (qt-16)*2; }
  else if (qt < 48) { nc = 3; off = 32 + (qt-32)*3; }
  else              { nc = 4; off = 80 + (qt-48)*4; }
  const int ubase = bh*144 + off;

  float m[4], l[4];
  float M = -1e30f;
#pragma unroll 4
  for (int cc=0; cc<4; cc++){
    if (cc < nc){
      m[cc] = ml[(size_t)(ubase+cc)*64 + r];
      l[cc] = ml[(size_t)(ubase+cc)*64 + 32 + r];
      M = fmaxf(M, m[cc]);
    }
  }
  float acc[8];
#pragma unroll
  for (int i=0;i<8;i++) acc[i] = 0.f;
  float denom = 0.f;
#pragma unroll 4
  for (int cc=0; cc<4; cc++){
    if (cc < nc){
      float w = exp2f((m[cc]-M)*L2E);
      denom += w*l[cc];
      const u16* sp = slot_cptr(pout, pwt, ubase+cc);
      bf16x8 v8 = *reinterpret_cast<const bf16x8*>(sp + (size_t)r*128 + dg*8);
#pragma unroll
      for (int i=0;i<8;i++) acc[i] += w*b2f((u16)v8[i]);
    }
  }
  float inv = 1.f/denom;
  bf16x8 o;
#pragma unroll
  for (int i=0;i<8;i++) o[i] = (short)f2b(acc[i]*inv);
  int b = bh >> 4, h = bh & 15;
  size_t row = (size_t)b*T_ + qt*32 + r;
  *reinterpret_cast<bf16x8*>(ao + row*2048 + h*128 + dg*8) = o;
}

// ---------------- launch ----------------
extern "C" void kernel_launch(void* const* d_in, const int* in_sizes, int n_in,
                              void* d_out, int out_size, void* d_ws, size_t ws_size,
                              hipStream_t stream)
{
  const float* x  = (const float*)d_in[0];
  const float* Wq = (const float*)d_in[1];
  const float* Wk = (const float*)d_in[2];
  const float* Wv = (const float*)d_in[3];
  const float* Wo = (const float*)d_in[4];
  float* out = (float*)d_out;

  char* ws = (char*)d_ws;
  size_t off = 0;
  auto carve = [&](size_t bytes)->void*{
    void* p = ws + off; off += (bytes + 255) & ~(size_t)255; return p;
  };
  u16*    xb   = (u16*)carve((size_t)M_*DM_*2);       // reused as `ao` after QKV GEMM
  u16*    wT   = (u16*)carve((size_t)QKVN*2048*2);    // [Wq;Wk;Wv]^T ; dead after QKV GEMM -> partial slots
  u16*    woT  = (u16*)carve((size_t)2048*2048*2);
  u16*    qkv  = (u16*)carve((size_t)M_*QKVN*2);
  u16*    vt   = (u16*)carve((size_t)M_*512*2);
  float2* tab  = (float2*)carve((size_t)T_*64*8);
  float*  ml   = (float*)carve((size_t)4608*64*4);
  u16*    ao   = xb;                                  // alias: xb dead after QKV GEMM
  u16*    pout = (u16*)d_out;                         // 4096 slots x 8KB, overwritten by final GEMM
  u16*    pwt  = wT;                                  // 512 slots x 8KB in dead wT region

  prep_kernel<<<18944, 256, 0, stream>>>(x, Wq, Wk, Wv, Wo, xb, wT, woT, tab);

  gemm_db<u16,256,4><<<dim3(12,16), 512, 0, stream>>>(xb, wT, qkv, M_, QKVN, 2048);

  mid_kernel<<<12288, 256, 0, stream>>>(qkv, tab, vt);

  attn_kernel<<<1280, 256, 0, stream>>>(qkv, vt, pout, pwt, ml, ao);
  combine_kernel<<<3072, 256, 0, stream>>>(pout, pwt, ml, ao);

  gemm_db<float,128,2><<<dim3(16,16), 512, 0, stream>>>(ao, woT, out, M_, 2048, 2048);
}

// Round 23
// 224.421 us; speedup vs baseline: 1.0174x; 1.0174x over previous
//
#include <hip/hip_runtime.h>
#include <hip/hip_bf16.h>
#include <type_traits>

#define B_ 2
#define T_ 2048
#define DM_ 2048
#define H_ 16
#define KV_ 4
#define HD_ 128
#define M_ 4096   // B_*T_
#define QKVN 3072 // H*HD + 2*KV*HD

typedef __attribute__((ext_vector_type(8))) short bf16x8;
typedef __attribute__((ext_vector_type(4))) float f32x4;
typedef __attribute__((ext_vector_type(4))) short s16x4;
typedef unsigned short u16;
typedef unsigned int u32;
typedef __attribute__((address_space(1))) unsigned int as1_u32;
typedef __attribute__((address_space(3))) unsigned int as3_u32;

__device__ inline u16 f2b(float f){
  __hip_bfloat16 h = __float2bfloat16(f);
  return *reinterpret_cast<u16*>(&h);
}
__device__ inline float b2f(u16 u){
  __hip_bfloat16 h = *reinterpret_cast<__hip_bfloat16*>(&u);
  return __bfloat162float(h);
}
__device__ inline f32x4 mfma16(bf16x8 a, bf16x8 b, f32x4 c){
  return __builtin_amdgcn_mfma_f32_16x16x32_bf16(a, b, c, 0, 0, 0);
}

// ---------------- fused prep: cvt + rope_table + 4x weight transpose ----------------
__global__ __launch_bounds__(256) void prep_kernel(const float* __restrict__ x,
                                                   const float* __restrict__ Wq,
                                                   const float* __restrict__ Wk,
                                                   const float* __restrict__ Wv,
                                                   const float* __restrict__ Wo,
                                                   u16* __restrict__ xb,
                                                   u16* __restrict__ wT,
                                                   u16* __restrict__ woT,
                                                   float2* __restrict__ tab)
{
  const int bid = blockIdx.x;
  const int tid = threadIdx.x;
  if (bid < 8192){
    int i = (bid*256 + tid)*4;
    float4 v = *reinterpret_cast<const float4*>(x + i);
    s16x4 o;
    o[0] = (short)f2b(v.x); o[1] = (short)f2b(v.y);
    o[2] = (short)f2b(v.z); o[3] = (short)f2b(v.w);
    *reinterpret_cast<s16x4*>(xb + i) = o;
    return;
  }
  if (bid < 8704){
    int idx = (bid-8192)*256 + tid;   // t*64 + d
    int t = idx >> 6, d = idx & 63;
    float inv = exp2f((float)d * -0.2076205059304601f);
    float sn, cs;
    sincosf((float)t * inv, &sn, &cs);
    tab[idx] = float2{cs, sn};
    return;
  }
  int r = bid - 8704;
  const float* W; u16* Wt; int N, nx;
  if (r < 4096)      { W = Wq; Wt = wT;               N = 2048; nx = 64; }
  else if (r < 5120) { W = Wk; Wt = wT + 2048*2048;   N = 512;  nx = 16; r -= 4096; }
  else if (r < 6144) { W = Wv; Wt = wT + 2560*2048;   N = 512;  nx = 16; r -= 5120; }
  else               { W = Wo; Wt = woT;              N = 2048; nx = 64; r -= 6144; }
  const int n0 = (r % nx)*32, k0 = (r / nx)*32;
  const int tx = tid & 31, ty = tid >> 5;
  __shared__ float tile[32][33];
#pragma unroll
  for (int i=0;i<4;i++)
    tile[ty+8*i][tx] = W[(size_t)(k0+ty+8*i)*N + n0 + tx];
  __syncthreads();
#pragma unroll
  for (int i=0;i<4;i++)
    Wt[(size_t)(n0+ty+8*i)*2048 + k0 + tx] = f2b(tile[tx][ty+8*i]);
}

// ---------------- fused mid: RoPE apply (Q+K) + transpose_v ----------------
// blocks [0,10240): rope (Q first 8192, K next 2048); [10240,12288): transpose_v
__global__ __launch_bounds__(256) void mid_kernel(u16* __restrict__ qkv, const float2* __restrict__ tab,
                                                  u16* __restrict__ vt)
{
  const int bid = blockIdx.x;
  const int tid = threadIdx.x;
  if (bid < 10240){
    u16* qk; int lognh, idx;
    if (bid < 8192){ qk = qkv;        lognh = 4; idx = bid*256 + tid; }
    else           { qk = qkv + 2048; lognh = 2; idx = (bid-8192)*256 + tid; }
    int dp = idx & 31;
    int rh = idx >> 5;
    int nh = 1 << lognh;
    int h = rh & (nh-1);
    int row = rh >> lognh;
    if (row >= M_) return;
    int t = row & (T_-1);
    float4 cn = *reinterpret_cast<const float4*>(tab + t*64 + 2*dp);
    size_t base = (size_t)row*QKVN + h*HD_ + 2*dp;
    u32 lo = *reinterpret_cast<const u32*>(qk + base);
    u32 hi = *reinterpret_cast<const u32*>(qk + base + 64);
    float a0 = b2f(lo & 0xffff), a1 = b2f(lo >> 16);
    float b0 = b2f(hi & 0xffff), b1 = b2f(hi >> 16);
    u32 nlo = (u32)f2b(a0*cn.x - b0*cn.y) | ((u32)f2b(a1*cn.z - b1*cn.w) << 16);
    u32 nhi = (u32)f2b(b0*cn.x + a0*cn.y) | ((u32)f2b(b1*cn.z + a1*cn.w) << 16);
    *reinterpret_cast<u32*>(qk + base)      = nlo;
    *reinterpret_cast<u32*>(qk + base + 64) = nhi;
    return;
  }
  // transpose_v
  const int bid2 = bid - 10240;
  const int t0 = (bid2 & 63)*32;
  const int d0 = ((bid2>>6)&3)*32;
  const int bk = bid2>>8;
  const int bb = bk >> 2, kv = bk & 3;
  const int tx = tid & 31, ty = tid >> 5;
  __shared__ u16 tile[32][33];
#pragma unroll
  for (int i=0;i<4;i++)
    tile[ty+8*i][tx] = qkv[(size_t)(bb*T_ + t0+ty+8*i)*QKVN + 2560 + kv*HD_ + d0 + tx];
  __syncthreads();
#pragma unroll
  for (int i=0;i<4;i++)
    vt[(size_t)(bk*HD_ + d0+ty+8*i)*T_ + t0 + tx] = tile[tx][ty+8*i];
}

// ---------------- bf16 GEMM v3: 256-row tile, double-buffered LDS, counted vmcnt ----------------
__device__ inline void cstore(float* p, float v){ *p = v; }
__device__ inline void cstore(u16* p, float v){ *p = f2b(v); }

template<typename CT, int BN, int NWC>
__global__ __launch_bounds__(512, 2) void gemm_db(const u16* __restrict__ A, const u16* __restrict__ BT,
                                                  CT* __restrict__ C, int M, int N, int K)
{
  constexpr int AP = 4;
  constexpr int BP = BN/64;
  constexpr int MR = 2*NWC;
  __shared__ u16 Als[2][256*64];
  __shared__ u16 Bls[2][BN*64];

  const int tid = threadIdx.x;
  const int wave = tid>>6, lane = tid&63;
  const int gl = lane>>4, qcl = lane&15;
  const int gx = gridDim.x;
  int wid = blockIdx.y*gx + blockIdx.x;
  const int cpx = (gx*gridDim.y) >> 3;
  wid = (wid & 7)*cpx + (wid >> 3);
  const int m0 = (wid / gx)*256, n0 = (wid % gx)*BN;
  const int wr = (wave / NWC)*(16*MR);
  const int wc = (wave % NWC)*64;

  f32x4 acc[MR][4];
#pragma unroll
  for (int i=0;i<MR;i++)
#pragma unroll
    for (int j=0;j<4;j++) acc[i][j] = f32x4{0.f,0.f,0.f,0.f};

  const u16* srcA[AP];
  const u16* srcB[BP];
#pragma unroll
  for (int p=0;p<AP;p++){
    const int D = p*8192 + tid*16;
    const int row = D>>7;
    const int colb = (((D>>4)&7) ^ (row&7))*8;
    srcA[p] = A + (size_t)(m0+row)*K + colb;
  }
#pragma unroll
  for (int p=0;p<BP;p++){
    const int D = p*8192 + tid*16;
    const int row = D>>7;
    const int colb = (((D>>4)&7) ^ (row&7))*8;
    srcB[p] = BT + (size_t)(n0+row)*K + colb;
  }

  auto stage = [&](int buf){
#pragma unroll
    for (int p=0;p<AP;p++)
      __builtin_amdgcn_global_load_lds((as1_u32*)srcA[p],
        (as3_u32*)((char*)&Als[buf][0] + p*8192 + wave*1024), 16, 0, 0);
#pragma unroll
    for (int p=0;p<BP;p++)
      __builtin_amdgcn_global_load_lds((as1_u32*)srcB[p],
        (as3_u32*)((char*)&Bls[buf][0] + p*8192 + wave*1024), 16, 0, 0);
#pragma unroll
    for (int p=0;p<AP;p++) srcA[p] += 64;
#pragma unroll
    for (int p=0;p<BP;p++) srcB[p] += 64;
  };

  auto compute = [&](int buf){
#pragma unroll
    for (int kk=0;kk<2;kk++){
      bf16x8 af[MR], bfr[4];
#pragma unroll
      for (int mi=0;mi<MR;mi++){
        const int row = wr + mi*16 + qcl;
        af[mi] = *reinterpret_cast<const bf16x8*>((char*)&Als[buf][0] + row*128 + (((kk<<2)+gl) ^ (qcl&7))*16);
      }
#pragma unroll
      for (int ni=0;ni<4;ni++){
        const int row = wc + ni*16 + qcl;
        bfr[ni] = *reinterpret_cast<const bf16x8*>((char*)&Bls[buf][0] + row*128 + (((kk<<2)+gl) ^ (qcl&7))*16);
      }
      __builtin_amdgcn_s_setprio(1);
#pragma unroll
      for (int mi=0;mi<MR;mi++)
#pragma unroll
        for (int ni=0;ni<4;ni++)
          acc[mi][ni] = mfma16(af[mi], bfr[ni], acc[mi][ni]);
      __builtin_amdgcn_s_setprio(0);
    }
  };

  const int NT = K >> 6;
  stage(0);
  for (int t=0; t<NT; t++){
    const int cur = t&1;
    if (t+1 < NT){
      stage(cur^1);
      if constexpr (AP+BP == 8) asm volatile("s_waitcnt vmcnt(8)" ::: "memory");
      else                      asm volatile("s_waitcnt vmcnt(6)" ::: "memory");
    } else {
      asm volatile("s_waitcnt vmcnt(0)" ::: "memory");
    }
    __builtin_amdgcn_s_barrier();
    compute(cur);
    __builtin_amdgcn_s_barrier();
  }

#pragma unroll
  for (int mi=0;mi<MR;mi++)
#pragma unroll
    for (int ni=0;ni<4;ni++)
#pragma unroll
      for (int j=0;j<4;j++){
        int row = m0 + wr + mi*16 + (lane>>4)*4 + j;
        int col = n0 + wc + ni*16 + (lane&15);
        cstore(C + (size_t)row*N + col, acc[mi][ni][j]);
      }
}

// ---------------- causal GQA flash attention (v14: per-qs softmax, reduced live range) ----------------
__device__ inline const u16* slot_cptr(const u16* pout, const u16* pwt, int u){
  return (u < 4096) ? (pout + (size_t)u*4096) : (pwt + (size_t)(u-4096)*4096);
}

__global__ __launch_bounds__(256, 3) void attn_kernel(const u16* __restrict__ qkv,
                                                      const u16* __restrict__ Vt,
                                                      u16* __restrict__ pout,
                                                      u16* __restrict__ pwt,
                                                      float* __restrict__ ml,
                                                      u16* __restrict__ ao)
{
  __shared__ u16 Ktile[2][4096];    // 2 x 8 KB, swizzled
  __shared__ u16 Vtile[2][4096];    // 2 x 8 KB, swizzled
  __shared__ u16 plds[4][32*40];    // per-wave P roundtrip
  const int wave = threadIdx.x>>6, lane = threadIdx.x&63;
  const int g = lane>>4, qc = lane&15;

  const int bh = blockIdx.x & 31;
  const int rem = blockIdx.x >> 5;  // 0..39
  int q4, e;
  if (rem < 4)       { q4=0; e=rem; }
  else if (rem < 12) { q4=1; e=rem-4; }
  else if (rem < 24) { q4=2; e=rem-12; }
  else               { q4=3; e=rem-24; }
  const int j  = q4*4 + e/(q4+1);
  const int c  = e%(q4+1);
  const int nc = q4 + 1;            // chunks for this q-group
  const int qt = j*4 + wave;        // this wave's 32-row q-tile
  const int ntg = j*4 + 4;          // staged tiles go to the group's max diagonal
  const int tstart = 16*c;
  const int tcnt = min(16, ntg - tstart);

  const int h = bh & (H_-1), b = bh >> 4;
  const int kv = h >> 2;

  const u16* qbase = qkv + (size_t)(b*T_ + qt*32)*QKVN + h*HD_ + 8*g;
  bf16x8 qf[2][4];
#pragma unroll
  for (int qs=0; qs<2; qs++)
#pragma unroll
    for (int d4=0; d4<4; d4++)
      qf[qs][d4] = *reinterpret_cast<const bf16x8*>(qbase + (size_t)(qs*16+qc)*QKVN + d4*32);

  const char* Kbase = (const char*)(qkv + (size_t)(b*T_)*QKVN + 2048 + kv*HD_);
  const char* Vbase = (const char*)(Vt + (size_t)(b*KV_+kv)*HD_*T_);
  const char* Ktc = (const char*)&Ktile[0][0];
  const char* Vtc = (const char*)&Vtile[0][0];

  f32x4 oacc[2][8];
#pragma unroll
  for (int qs=0; qs<2; qs++)
#pragma unroll
    for (int dt=0; dt<8; dt++) oacc[qs][dt] = f32x4{0.f,0.f,0.f,0.f};
  float mrun[2] = {-1e30f, -1e30f};
  float lrun[2] = {0.f, 0.f};
  const float SCALE = 0.08838834764831845f;
  const float L2E = 1.4426950408889634f;
  const float DEFER = 8.f;          // T13
  u16* pw = &plds[wave][0];

  auto compute = [&](int t, int half, auto mc){
    constexpr bool masked = decltype(mc)::value;
    const int s0 = t*32;
    const int hb = half*8192;       // byte offset of buffer half
    f32x4 sacc[2][2];
#pragma unroll
    for (int qs=0; qs<2; qs++)
#pragma unroll
      for (int ss=0; ss<2; ss++) sacc[qs][ss] = f32x4{0.f,0.f,0.f,0.f};
    __builtin_amdgcn_s_setprio(1);
#pragma unroll
    for (int d4=0; d4<4; d4++)
#pragma unroll
      for (int ss=0; ss<2; ss++){
        int A = ((ss*16+qc)<<8) + (d4<<6) + (g<<4);
        A ^= (qc&7)<<4;                      // K un-swizzle (row&7 == qc&7)
        bf16x8 kf = *reinterpret_cast<const bf16x8*>(Ktc + hb + A);
#pragma unroll
        for (int qs=0; qs<2; qs++)
          sacc[qs][ss] = mfma16(kf, qf[qs][d4], sacc[qs][ss]);
      }
    __builtin_amdgcn_s_setprio(0);

    // per-qs softmax: halves the live p[] range (spill control)
#pragma unroll
    for (int qs=0; qs<2; qs++){
      float p[8];
      float tm = -1e30f;
#pragma unroll
      for (int ss=0; ss<2; ss++)
#pragma unroll
        for (int jj=0; jj<4; jj++){
          float v = sacc[qs][ss][jj]*SCALE;
          if constexpr (masked){
            int sg = s0 + ss*16 + g*4 + jj;
            if (sg > qt*32 + qs*16 + qc) v = -1e30f;
          }
          p[ss*4+jj] = v;
          tm = fmaxf(tm, v);
        }
      tm = fmaxf(tm, __shfl_xor(tm, 16));
      tm = fmaxf(tm, __shfl_xor(tm, 32));
      float mnew = fmaxf(mrun[qs], tm);
      if (tm - mrun[qs] <= DEFER) mnew = mrun[qs];   // defer-max
      float al = exp2f((mrun[qs]-mnew)*L2E);
      float rs = 0.f;
#pragma unroll
      for (int i=0;i<8;i++){ p[i] = exp2f((p[i]-mnew)*L2E); rs += p[i]; }
      rs += __shfl_xor(rs, 16);
      rs += __shfl_xor(rs, 32);
      lrun[qs] = lrun[qs]*al + rs;
      mrun[qs] = mnew;
      if (!__all(al==1.f)){
        float aj[4];
#pragma unroll
        for (int jj=0; jj<4; jj++) aj[jj] = __shfl(al, g*4+jj);
#pragma unroll
        for (int dt=0; dt<8; dt++)
#pragma unroll
          for (int jj=0; jj<4; jj++) oacc[qs][dt][jj] *= aj[jj];
      }
#pragma unroll
      for (int ss=0; ss<2; ss++){
        unsigned w0 = (unsigned)f2b(p[ss*4+0]) | ((unsigned)f2b(p[ss*4+1])<<16);
        unsigned w1 = (unsigned)f2b(p[ss*4+2]) | ((unsigned)f2b(p[ss*4+3])<<16);
        *reinterpret_cast<unsigned*>(pw + (qs*16+qc)*40 + ss*16 + g*4)     = w0;
        *reinterpret_cast<unsigned*>(pw + (qs*16+qc)*40 + ss*16 + g*4 + 2) = w1;
      }
    }
    bf16x8 pf[2];
#pragma unroll
    for (int qs=0; qs<2; qs++)
      pf[qs] = *reinterpret_cast<const bf16x8*>(pw + (qs*16+qc)*40 + 8*g);
    __builtin_amdgcn_s_setprio(1);
#pragma unroll
    for (int dt=0; dt<8; dt++){
      int A = ((dt*16+qc)<<6) + (g<<4);
      A ^= ((qc>>1)&3)<<4;                   // V un-swizzle ((row>>1)&3 == (qc>>1)&3)
      bf16x8 vf = *reinterpret_cast<const bf16x8*>(Vtc + hb + A);
#pragma unroll
      for (int qs=0; qs<2; qs++)
        oacc[qs][dt] = mfma16(pf[qs], vf, oacc[qs][dt]);
    }
    __builtin_amdgcn_s_setprio(0);
  };
  using Tc = std::integral_constant<bool,true>;
  using Fc = std::integral_constant<bool,false>;

  // ---- main loop: stage 2 tiles (shared) -> barrier -> compute 2 ----
  const int npair = (tcnt+1)>>1;
  for (int ip = 0; ip < npair; ip++){
    const int t0 = tstart + 2*ip;
    const int ntile = min(2, tstart + tcnt - t0);
    __syncthreads();                          // previous tiles' LDS reads done
#pragma unroll
    for (int tt=0; tt<2; tt++){
      if (tt < ntile){
        const size_t r0 = (size_t)(t0+tt)*32;
#pragma unroll
        for (int c2=0; c2<2; c2++){
          const int cc = wave*2 + c2;
          const int D = cc*1024 + lane*16;
          // K: [32 s][128 d] rows 256B, swizzle byte ^= (row&7)<<4
          {
            const int LK = D ^ (((D>>8)&7)<<4);
            const char* src = Kbase + (r0 + (size_t)(D>>8))*(QKVN*2) + (LK & 255);
            __builtin_amdgcn_global_load_lds((as1_u32*)src,
              (as3_u32*)((char*)&Ktile[0][0] + tt*8192 + cc*1024), 16, 0, 0);
          }
          // V^T: [128 d][32 s] rows 64B, swizzle byte ^= ((row>>1)&3)<<4
          {
            const int LV = (D&63) ^ (((D>>7)&3)<<4);
            const char* src = Vbase + ((size_t)(D>>6)*T_ + r0 + (LV>>1))*2;
            __builtin_amdgcn_global_load_lds((as1_u32*)src,
              (as3_u32*)((char*)&Vtile[0][0] + tt*8192 + cc*1024), 16, 0, 0);
          }
        }
      }
    }
    __syncthreads();                          // vmcnt drained before barrier -> tiles ready
    if (t0 < qt)       compute(t0,   0, Fc{});
    else if (t0 == qt) compute(t0,   0, Tc{});
    if (ntile > 1){
      if (t0+1 < qt)       compute(t0+1, 1, Fc{});
      else if (t0+1 == qt) compute(t0+1, 1, Tc{});
    }
  }

  if (nc == 1){
    // qt < 16: finalize directly
    float lj0[4], lj1[4];
    float li0 = 1.f/lrun[0], li1 = 1.f/lrun[1];
#pragma unroll
    for (int jj=0; jj<4; jj++){
      lj0[jj] = __shfl(li0, g*4+jj);
      lj1[jj] = __shfl(li1, g*4+jj);
    }
    u16* ob = ao + (size_t)(b*T_ + qt*32)*(H_*HD_) + h*HD_;
#pragma unroll
    for (int dt=0; dt<8; dt++)
#pragma unroll
      for (int jj=0; jj<4; jj++){
        ob[(size_t)(g*4+jj)*(H_*HD_) + dt*16 + qc]      = f2b(oacc[0][dt][jj]*lj0[jj]);
        ob[(size_t)(16 + g*4+jj)*(H_*HD_) + dt*16 + qc] = f2b(oacc[1][dt][jj]*lj1[jj]);
      }
  } else {
    // slot = bh*144 + off(qt) + c
    int off;
    if (qt < 32)      off = (qt-16)*2;
    else if (qt < 48) off = 32 + (qt-32)*3;
    else              off = 80 + (qt-48)*4;
    const int u = bh*144 + off + c;
    u16* ob = (u < 4096) ? (pout + (size_t)u*4096) : (pwt + (size_t)(u-4096)*4096);
#pragma unroll
    for (int qs=0; qs<2; qs++)
#pragma unroll
      for (int dt=0; dt<8; dt++)
#pragma unroll
        for (int jj=0; jj<4; jj++)
          ob[(size_t)(qs*16 + g*4+jj)*128 + dt*16 + qc] = f2b(oacc[qs][dt][jj]);
    if (lane < 16){
      float* mlb = ml + (size_t)u*64;
#pragma unroll
      for (int qs=0; qs<2; qs++){
        mlb[qs*16 + lane]      = mrun[qs];
        mlb[32 + qs*16 + lane] = lrun[qs];
      }
    }
  }
}

// ---------------- combine partials (qt>=16) -> attention output (bf16) ----------------
__global__ void combine_kernel(const u16* __restrict__ pout, const u16* __restrict__ pwt,
                               const float* __restrict__ ml, u16* __restrict__ ao)
{
  const float L2E = 1.4426950408889634f;
  int idx = blockIdx.x*256 + threadIdx.x;   // 786432 threads
  int dg = idx & 15;
  int r  = (idx >> 4) & 31;
  int t  = idx >> 9;            // [0, 1536)
  int bh = t/48, qi = t%48;
  int qt = 16 + qi;
  int nc, off;
  if (qt < 32)      { nc = 2; off = (qt-16)*2; }
  else if (qt < 48) { nc = 3; off = 32 + (qt-32)*3; }
  else              { nc = 4; off = 80 + (qt-48)*4; }
  const int ubase = bh*144 + off;

  float m[4], l[4];
  float M = -1e30f;
#pragma unroll 4
  for (int cc=0; cc<4; cc++){
    if (cc < nc){
      m[cc] = ml[(size_t)(ubase+cc)*64 + r];
      l[cc] = ml[(size_t)(ubase+cc)*64 + 32 + r];
      M = fmaxf(M, m[cc]);
    }
  }
  float acc[8];
#pragma unroll
  for (int i=0;i<8;i++) acc[i] = 0.f;
  float denom = 0.f;
#pragma unroll 4
  for (int cc=0; cc<4; cc++){
    if (cc < nc){
      float w = exp2f((m[cc]-M)*L2E);
      denom += w*l[cc];
      const u16* sp = slot_cptr(pout, pwt, ubase+cc);
      bf16x8 v8 = *reinterpret_cast<const bf16x8*>(sp + (size_t)r*128 + dg*8);
#pragma unroll
      for (int i=0;i<8;i++) acc[i] += w*b2f((u16)v8[i]);
    }
  }
  float inv = 1.f/denom;
  bf16x8 o;
#pragma unroll
  for (int i=0;i<8;i++) o[i] = (short)f2b(acc[i]*inv);
  int b = bh >> 4, h = bh & 15;
  size_t row = (size_t)b*T_ + qt*32 + r;
  *reinterpret_cast<bf16x8*>(ao + row*2048 + h*128 + dg*8) = o;
}

// ---------------- launch ----------------
extern "C" void kernel_launch(void* const* d_in, const int* in_sizes, int n_in,
                              void* d_out, int out_size, void* d_ws, size_t ws_size,
                              hipStream_t stream)
{
  const float* x  = (const float*)d_in[0];
  const float* Wq = (const float*)d_in[1];
  const float* Wk = (const float*)d_in[2];
  const float* Wv = (const float*)d_in[3];
  const float* Wo = (const float*)d_in[4];
  float* out = (float*)d_out;

  char* ws = (char*)d_ws;
  size_t off = 0;
  auto carve = [&](size_t bytes)->void*{
    void* p = ws + off; off += (bytes + 255) & ~(size_t)255; return p;
  };
  u16*    xb   = (u16*)carve((size_t)M_*DM_*2);       // reused as `ao` after QKV GEMM
  u16*    wT   = (u16*)carve((size_t)QKVN*2048*2);    // [Wq;Wk;Wv]^T ; dead after QKV GEMM -> partial slots
  u16*    woT  = (u16*)carve((size_t)2048*2048*2);
  u16*    qkv  = (u16*)carve((size_t)M_*QKVN*2);
  u16*    vt   = (u16*)carve((size_t)M_*512*2);
  float2* tab  = (float2*)carve((size_t)T_*64*8);
  float*  ml   = (float*)carve((size_t)4608*64*4);
  u16*    ao   = xb;                                  // alias: xb dead after QKV GEMM
  u16*    pout = (u16*)d_out;                         // 4096 slots x 8KB, overwritten by final GEMM
  u16*    pwt  = wT;                                  // 512 slots x 8KB in dead wT region

  prep_kernel<<<18944, 256, 0, stream>>>(x, Wq, Wk, Wv, Wo, xb, wT, woT, tab);

  gemm_db<u16,256,4><<<dim3(12,16), 512, 0, stream>>>(xb, wT, qkv, M_, QKVN, 2048);

  mid_kernel<<<12288, 256, 0, stream>>>(qkv, tab, vt);

  attn_kernel<<<1280, 256, 0, stream>>>(qkv, vt, pout, pwt, ml, ao);
  combine_kernel<<<3072, 256, 0, stream>>>(pout, pwt, ml, ao);

  gemm_db<float,128,2><<<dim3(16,16), 512, 0, stream>>>(ao, woT, out, M_, 2048, 2048);
}